// Round 1
// baseline (1277.355 us; speedup 1.0000x reference)
//
#include <hip/hip_runtime.h>
#include <math.h>

// ---------------------------------------------------------------------------
// Generic fp32 GEMM: C = A(MxK) @ B(KxN) + bias [+ resid], optional ReLU.
// BM=BN=64, BK=16, 256 threads, 4x4 per thread. All dims multiples of 64/16.
// ---------------------------------------------------------------------------
__global__ __launch_bounds__(256) void gemm_kernel(
    const float* __restrict__ A, int lda,
    const float* __restrict__ B, int ldb,
    const float* __restrict__ bias,
    const float* __restrict__ resid, int ldr,
    float* __restrict__ C, int ldc,
    int M, int N, int K, int relu)
{
    __shared__ float As[16][64 + 1];   // [k][m]
    __shared__ float Bs[16][64 + 1];   // [k][n]
    int tid = threadIdx.x;
    int tx = tid & 15, ty = tid >> 4;
    int m0 = blockIdx.x * 64;
    int n0 = blockIdx.y * 64;
    float acc[4][4] = {};

    for (int k0 = 0; k0 < K; k0 += 16) {
#pragma unroll
        for (int j = 0; j < 4; ++j) {
            int idx = tid + j * 256;          // 0..1023
            int m = idx >> 4, k = idx & 15;   // A tile 64x16
            As[k][m] = A[(size_t)(m0 + m) * lda + k0 + k];
        }
#pragma unroll
        for (int j = 0; j < 4; ++j) {
            int idx = tid + j * 256;
            int k = idx >> 6, n = idx & 63;   // B tile 16x64
            Bs[k][n] = B[(size_t)(k0 + k) * ldb + n0 + n];
        }
        __syncthreads();
#pragma unroll
        for (int kk = 0; kk < 16; ++kk) {
            float a[4], b[4];
#pragma unroll
            for (int i = 0; i < 4; ++i) a[i] = As[kk][ty * 4 + i];
#pragma unroll
            for (int i = 0; i < 4; ++i) b[i] = Bs[kk][tx * 4 + i];
#pragma unroll
            for (int i = 0; i < 4; ++i)
#pragma unroll
                for (int j = 0; j < 4; ++j)
                    acc[i][j] = fmaf(a[i], b[j], acc[i][j]);
        }
        __syncthreads();
    }

#pragma unroll
    for (int i = 0; i < 4; ++i) {
        int m = m0 + ty * 4 + i;
#pragma unroll
        for (int j = 0; j < 4; ++j) {
            int n = n0 + tx * 4 + j;
            float v = acc[i][j];
            if (bias)  v += bias[n];
            if (resid) v += resid[(size_t)m * ldr + n];
            if (relu)  v = fmaxf(v, 0.f);
            C[(size_t)m * ldc + n] = v;
        }
    }
}

// ---------------------------------------------------------------------------
// Scores: heat[hb][s][t] = Q[b*S+s, h*64:..] . K[b*S+t, h*64:..]  (unscaled)
// grid (HB, S/64, S/64), 256 threads, 64x64 tile, K=64.
// ---------------------------------------------------------------------------
__global__ __launch_bounds__(256) void scores_kernel(
    const float* __restrict__ Q, const float* __restrict__ Km,
    float* __restrict__ heat, int S, int B)
{
    int hb = blockIdx.x;
    int h = hb / B, b = hb % B;
    int s0 = blockIdx.y * 64, t0 = blockIdx.z * 64;
    const float* Qp = Q  + (size_t)b * S * 512 + h * 64;
    const float* Kp = Km + (size_t)b * S * 512 + h * 64;

    __shared__ float Qs[64][64 + 1];   // [k][s]
    __shared__ float Ks[64][64 + 1];   // [k][t]
    int tid = threadIdx.x, tx = tid & 15, ty = tid >> 4;

#pragma unroll
    for (int j = 0; j < 16; ++j) {
        int idx = tid + j * 256;
        int r = idx >> 6, c = idx & 63;
        Qs[c][r] = Qp[(size_t)(s0 + r) * 512 + c];
        Ks[c][r] = Kp[(size_t)(t0 + r) * 512 + c];
    }
    __syncthreads();

    float acc[4][4] = {};
    for (int kk = 0; kk < 64; ++kk) {
        float a[4], bb[4];
#pragma unroll
        for (int i = 0; i < 4; ++i) a[i]  = Qs[kk][ty * 4 + i];
#pragma unroll
        for (int i = 0; i < 4; ++i) bb[i] = Ks[kk][tx * 4 + i];
#pragma unroll
        for (int i = 0; i < 4; ++i)
#pragma unroll
            for (int j = 0; j < 4; ++j)
                acc[i][j] = fmaf(a[i], bb[j], acc[i][j]);
    }

    size_t base = ((size_t)hb * S + s0) * S + t0;
#pragma unroll
    for (int i = 0; i < 4; ++i)
#pragma unroll
        for (int j = 0; j < 4; ++j)
            heat[base + (size_t)(ty * 4 + i) * S + tx * 4 + j] = acc[i][j];
}

// ---------------------------------------------------------------------------
// Row stats: online max/sumexp over causal prefix t<=s of heat row.
// One wave per row. row = hb*S + s.
// ---------------------------------------------------------------------------
__global__ __launch_bounds__(64) void stats_kernel(
    const float* __restrict__ heat, float* __restrict__ mrow,
    float* __restrict__ lrow, int S)
{
    int row = blockIdx.x;
    int s = row & (S - 1);
    int lane = threadIdx.x;
    const float* r = heat + (size_t)row * S;

    float m = -1e30f, l = 0.f;
    for (int t = lane; t <= s; t += 64) {
        float v = r[t];
        float nm = fmaxf(m, v);
        l = l * __expf(m - nm) + __expf(v - nm);
        m = nm;
    }
#pragma unroll
    for (int off = 32; off; off >>= 1) {
        float mo = __shfl_down(m, off);
        float lo = __shfl_down(l, off);
        float nm = fmaxf(m, mo);
        l = l * __expf(m - nm) + lo * __expf(mo - nm);
        m = nm;
    }
    if (lane == 0) { mrow[row] = m; lrow[row] = l; }
}

// ---------------------------------------------------------------------------
// PV: wv[b*S+s, h*64+v] = sum_{t<=s} exp(heat[hb][s][t]-m[s])/l[s] * V[b*S+t, h*64+v]
// grid (HB, S/64), 256 threads, 64 rows x 64 vdim per block.
// ---------------------------------------------------------------------------
__global__ __launch_bounds__(256) void pv_kernel(
    const float* __restrict__ heat, const float* __restrict__ V,
    const float* __restrict__ mrow, const float* __restrict__ lrow,
    float* __restrict__ wv, int S, int B)
{
    int hb = blockIdx.x;
    int h = hb / B, b = hb % B;
    int s0 = blockIdx.y * 64;
    const float* Vp = V  + (size_t)b * S * 512 + h * 64;
    float*       Wp = wv + (size_t)b * S * 512 + h * 64;

    __shared__ float Ps[64][64 + 1];   // [t][s]  (p = exp(score - m))
    __shared__ float Vs[64][64 + 1];   // [t][v]
    __shared__ float ms[64], ls[64];

    int tid = threadIdx.x, tx = tid & 15, ty = tid >> 4;
    if (tid < 64) {
        ms[tid] = mrow[(size_t)hb * S + s0 + tid];
        ls[tid] = lrow[(size_t)hb * S + s0 + tid];
    }
    __syncthreads();

    float acc[4][4] = {};
    int ntiles = (s0 + 64) / 64;
    for (int kt = 0; kt < ntiles; ++kt) {
        int t0 = kt * 64;
        __syncthreads();
#pragma unroll
        for (int j = 0; j < 16; ++j) {
            int idx = tid + j * 256;
            int r = idx >> 6, c = idx & 63;
            int sg = s0 + r, tg = t0 + c;
            float sc = heat[((size_t)hb * S + sg) * S + tg];
            Ps[c][r] = (tg <= sg) ? __expf(sc - ms[r]) : 0.f;
            Vs[r][c] = Vp[(size_t)(t0 + r) * 512 + c];
        }
        __syncthreads();
        for (int kk = 0; kk < 64; ++kk) {
            float a[4], bb[4];
#pragma unroll
            for (int i = 0; i < 4; ++i) a[i]  = Ps[kk][ty * 4 + i];
#pragma unroll
            for (int i = 0; i < 4; ++i) bb[i] = Vs[kk][tx * 4 + i];
#pragma unroll
            for (int i = 0; i < 4; ++i)
#pragma unroll
                for (int j = 0; j < 4; ++j)
                    acc[i][j] = fmaf(a[i], bb[j], acc[i][j]);
        }
    }

#pragma unroll
    for (int i = 0; i < 4; ++i) {
        int r = ty * 4 + i;
        float inv = 1.0f / ls[r];
#pragma unroll
        for (int j = 0; j < 4; ++j)
            Wp[(size_t)(s0 + r) * 512 + tx * 4 + j] = acc[i][j] * inv;
    }
}

// ---------------------------------------------------------------------------
// LayerNorm over last dim 512. One block (256 thr) per row.
// ---------------------------------------------------------------------------
__device__ __forceinline__ float block_sum256(float v, float* sm) {
#pragma unroll
    for (int off = 32; off; off >>= 1) v += __shfl_down(v, off);
    __syncthreads();
    if ((threadIdx.x & 63) == 0) sm[threadIdx.x >> 6] = v;
    __syncthreads();
    return sm[0] + sm[1] + sm[2] + sm[3];
}

__global__ __launch_bounds__(256) void ln_kernel(
    const float* __restrict__ in, const float* __restrict__ g,
    const float* __restrict__ bta, float* __restrict__ out)
{
    __shared__ float sm[4];
    int row = blockIdx.x, tid = threadIdx.x;
    const float* r = in + (size_t)row * 512;
    float v0 = r[tid], v1 = r[tid + 256];
    float mu = block_sum256(v0 + v1, sm) * (1.f / 512.f);
    float d0 = v0 - mu, d1 = v1 - mu;
    float var = block_sum256(d0 * d0 + d1 * d1, sm) * (1.f / 512.f);
    float rs = rsqrtf(var + 1e-5f);
    out[(size_t)row * 512 + tid]       = d0 * rs * g[tid] + bta[tid];
    out[(size_t)row * 512 + tid + 256] = d1 * rs * g[tid + 256] + bta[tid + 256];
}

// ---------------------------------------------------------------------------
extern "C" void kernel_launch(void* const* d_in, const int* in_sizes, int n_in,
                              void* d_out, int out_size, void* d_ws, size_t ws_size,
                              hipStream_t stream)
{
    const float* x    = (const float*)d_in[0];
    const float* Wq   = (const float*)d_in[1];
    const float* bq   = (const float*)d_in[2];
    const float* Wk   = (const float*)d_in[3];
    const float* bk   = (const float*)d_in[4];
    const float* Wv   = (const float*)d_in[5];
    const float* bv   = (const float*)d_in[6];
    const float* Wo   = (const float*)d_in[7];
    const float* bo   = (const float*)d_in[8];
    const float* W1   = (const float*)d_in[9];
    const float* b1   = (const float*)d_in[10];
    const float* W2   = (const float*)d_in[11];
    const float* b2   = (const float*)d_in[12];
    const float* ln1g = (const float*)d_in[13];
    const float* ln1b = (const float*)d_in[14];
    const float* ln2g = (const float*)d_in[15];
    const float* ln2b = (const float*)d_in[16];

    const int B = 2, S = 2048, D = 512, T = B * S, HD = 2048, HB = 16;

    float* ws   = (float*)d_ws;
    float* Qb   = ws;                       // T*D
    float* Kb   = Qb + (size_t)T * D;       // T*D
    float* Vb   = Kb + (size_t)T * D;       // T*D
    float* wv   = Vb + (size_t)T * D;       // T*D
    float* hid  = Qb;                       // reuse Q..wv: T*HD == 4*T*D
    float* mrow = wv + (size_t)T * D;       // HB*S
    float* lrow = mrow + (size_t)HB * S;    // HB*S
    float* tmp  = lrow + (size_t)HB * S;    // T*D
    float* x1   = tmp + (size_t)T * D;      // T*D

    float* out_x2 = (float*)d_out;
    float* heat   = out_x2 + (size_t)T * D; // HB*S*S

    // QKV projections
    gemm_kernel<<<dim3(T / 64, D / 64), 256, 0, stream>>>(
        x, D, Wq, D, bq, nullptr, 0, Qb, D, T, D, D, 0);
    gemm_kernel<<<dim3(T / 64, D / 64), 256, 0, stream>>>(
        x, D, Wk, D, bk, nullptr, 0, Kb, D, T, D, D, 0);
    gemm_kernel<<<dim3(T / 64, D / 64), 256, 0, stream>>>(
        x, D, Wv, D, bv, nullptr, 0, Vb, D, T, D, D, 0);

    // Raw scores -> heatmap (unmasked), directly into d_out
    scores_kernel<<<dim3(HB, S / 64, S / 64), 256, 0, stream>>>(Qb, Kb, heat, S, B);

    // Causal softmax stats per row
    stats_kernel<<<dim3(HB * S), 64, 0, stream>>>(heat, mrow, lrow, S);

    // PV
    pv_kernel<<<dim3(HB, S / 64), 256, 0, stream>>>(heat, Vb, mrow, lrow, wv, S, B);

    // Output projection + residual, LN1
    gemm_kernel<<<dim3(T / 64, D / 64), 256, 0, stream>>>(
        wv, D, Wo, D, bo, x, D, tmp, D, T, D, D, 0);
    ln_kernel<<<dim3(T), 256, 0, stream>>>(tmp, ln1g, ln1b, x1);

    // FFN
    gemm_kernel<<<dim3(T / 64, HD / 64), 256, 0, stream>>>(
        x1, D, W1, HD, b1, nullptr, 0, hid, HD, T, HD, D, 1);
    gemm_kernel<<<dim3(T / 64, D / 64), 256, 0, stream>>>(
        hid, HD, W2, D, b2, x1, D, tmp, D, T, D, HD, 0);
    ln_kernel<<<dim3(T), 256, 0, stream>>>(tmp, ln2g, ln2b, out_x2);
}

// Round 3
// 301.446 us; speedup vs baseline: 4.2374x; 4.2374x over previous
//
#include <hip/hip_runtime.h>
#include <math.h>

typedef __attribute__((ext_vector_type(8))) short short8;
typedef __attribute__((ext_vector_type(4))) float f32x4;

__device__ __forceinline__ short f2bf(float f) {
    union { float f; unsigned u; } v; v.f = f;
    unsigned r = v.u + 0x7fff + ((v.u >> 16) & 1);
    return (short)(r >> 16);
}

// ---------------------------------------------------------------------------
// fp32 -> bf16 elementwise (vectorized x4)
// ---------------------------------------------------------------------------
__global__ __launch_bounds__(256) void convert_bf16_kernel(
    const float* __restrict__ in, short* __restrict__ out, int n)
{
    int i = (blockIdx.x * 256 + threadIdx.x) * 4;
    if (i >= n) return;
    float4 v = *reinterpret_cast<const float4*>(&in[i]);
    short4 o;
    o.x = f2bf(v.x); o.y = f2bf(v.y); o.z = f2bf(v.z); o.w = f2bf(v.w);
    *reinterpret_cast<short4*>(&out[i]) = o;
}

__global__ void pack_bias_kernel(const float* __restrict__ bq,
                                 const float* __restrict__ bk,
                                 const float* __restrict__ bv,
                                 float* __restrict__ out)
{
    int i = blockIdx.x * 256 + threadIdx.x;
    if (i >= 1536) return;
    out[i] = (i < 512) ? bq[i] : (i < 1024 ? bk[i - 512] : bv[i - 1024]);
}

// ---------------------------------------------------------------------------
// W [K][N] fp32  ->  Wt [N][K] bf16   (LDS 32x32 tile transpose)
// ---------------------------------------------------------------------------
__global__ __launch_bounds__(256) void transpose_convert_kernel(
    const float* __restrict__ W, short* __restrict__ Wt, int K, int N)
{
    __shared__ float t[32][33];
    int k0 = blockIdx.x * 32, n0 = blockIdx.y * 32;
    int tx = threadIdx.x & 31, ty = threadIdx.x >> 5;
#pragma unroll
    for (int r = ty; r < 32; r += 8)
        t[r][tx] = W[(size_t)(k0 + r) * N + n0 + tx];
    __syncthreads();
#pragma unroll
    for (int r = ty; r < 32; r += 8)
        Wt[(size_t)(n0 + r) * K + k0 + tx] = f2bf(t[tx][r]);
}

// ---------------------------------------------------------------------------
// bf16 MFMA GEMM: C = A(MxK) @ Bt(NxK)^T + bias [+resid] [relu]
// BM = MI*32 (MI=4 -> 128, MI=2 -> 64), BN = 128, BK = 32. 4 waves.
// Wave (wm,wn) owns (MI*16) x 64 output; MI x 4 fragments of 16x16.
// ---------------------------------------------------------------------------
template<int MI>
__global__ __launch_bounds__(256) void gemm_mfma(
    const short* __restrict__ A, int lda,
    const short* __restrict__ Bt, int ldb,
    const float* __restrict__ bias,
    const float* __restrict__ resid,
    float* __restrict__ Cf, short* __restrict__ Cb,
    int M, int N, int K, int relu)
{
    constexpr int BM = MI * 32;
    __shared__ short Al[BM][40];
    __shared__ short Bl[128][40];
    int tid = threadIdx.x;
    int wid = tid >> 6, lane = tid & 63;
    int g = lane >> 4, c = lane & 15;
    int wm = wid >> 1, wn = wid & 1;
    size_t m0 = (size_t)blockIdx.x * BM;
    size_t n0 = (size_t)blockIdx.y * 128;

    f32x4 acc[MI][4];
#pragma unroll
    for (int i = 0; i < MI; ++i)
#pragma unroll
        for (int j = 0; j < 4; ++j)
            acc[i][j] = (f32x4){0.f, 0.f, 0.f, 0.f};

    for (int k0 = 0; k0 < K; k0 += 32) {
        __syncthreads();
        // A tile: BM rows x 32 cols of shorts = BM*4 short8 quanta
#pragma unroll
        for (int i = tid; i < BM * 4; i += 256) {
            int row = i >> 2, q = i & 3;
            *reinterpret_cast<short8*>(&Al[row][q * 8]) =
                *reinterpret_cast<const short8*>(A + (m0 + row) * lda + k0 + q * 8);
        }
        // B tile: 128 rows x 32 cols = 512 short8 quanta
#pragma unroll
        for (int i = tid; i < 512; i += 256) {
            int row = i >> 2, q = i & 3;
            *reinterpret_cast<short8*>(&Bl[row][q * 8]) =
                *reinterpret_cast<const short8*>(Bt + (n0 + row) * ldb + k0 + q * 8);
        }
        __syncthreads();
        short8 a[MI], b[4];
#pragma unroll
        for (int mi = 0; mi < MI; ++mi)
            a[mi] = *reinterpret_cast<const short8*>(&Al[wm * (MI * 16) + mi * 16 + c][g * 8]);
#pragma unroll
        for (int ni = 0; ni < 4; ++ni)
            b[ni] = *reinterpret_cast<const short8*>(&Bl[wn * 64 + ni * 16 + c][g * 8]);
#pragma unroll
        for (int mi = 0; mi < MI; ++mi)
#pragma unroll
            for (int ni = 0; ni < 4; ++ni)
                acc[mi][ni] = __builtin_amdgcn_mfma_f32_16x16x32_bf16(
                    a[mi], b[ni], acc[mi][ni], 0, 0, 0);
    }

#pragma unroll
    for (int mi = 0; mi < MI; ++mi)
#pragma unroll
        for (int ni = 0; ni < 4; ++ni)
#pragma unroll
            for (int r = 0; r < 4; ++r) {
                size_t m = m0 + wm * (MI * 16) + mi * 16 + g * 4 + r;
                size_t n = n0 + wn * 64 + ni * 16 + c;
                float v = acc[mi][ni][r];
                if (bias)  v += bias[n];
                if (resid) v += resid[m * N + n];
                if (relu)  v = fmaxf(v, 0.f);
                if (Cf) Cf[m * N + n] = v;
                if (Cb) Cb[m * N + n] = f2bf(v);
            }
}

// ---------------------------------------------------------------------------
// Fused flash attention + full heatmap write.
// QKV bf16 [4096][1536] (cols 0-511 Q, 512-1023 K, 1024-1535 V, head-major 64).
// grid (HB=16, S/64=32), 256 threads = 4 waves; wave owns 16 q-rows.
// Every block computes ALL 32 t-tiles (heatmap needs full S x S), softmax/PV
// only on causal tiles.
// ---------------------------------------------------------------------------
__global__ __launch_bounds__(256) void attn_kernel(
    const short* __restrict__ QKV,
    float* __restrict__ heat,
    short* __restrict__ wv)
{
    constexpr int S = 2048;
    constexpr int LD = 1536;
    __shared__ short Kl[64][72];
    __shared__ short Vt[64][72];       // transposed: Vt[v][t]
    __shared__ short Pl[4][16][72];    // per-wave P, [s][t]

    int tid = threadIdx.x;
    int wid = tid >> 6, lane = tid & 63;
    int g = lane >> 4, c = lane & 15;
    int hb = blockIdx.x, h = hb >> 1, b = hb & 1;
    int s0 = blockIdx.y * 64;
    int sbase = s0 + wid * 16;

    // Q fragments (A-layout): row = lane&15, k = (lane>>4)*8 + i
    short8 q0, q1;
    {
        const short* qp = QKV + (size_t)(b * S + sbase + c) * LD + h * 64 + g * 8;
        q0 = *reinterpret_cast<const short8*>(qp);
        q1 = *reinterpret_cast<const short8*>(qp + 32);
    }

    f32x4 o[4];
    float m_run[4], l_run[4];
#pragma unroll
    for (int ni = 0; ni < 4; ++ni) o[ni] = (f32x4){0.f, 0.f, 0.f, 0.f};
#pragma unroll
    for (int r = 0; r < 4; ++r) { m_run[r] = -1e30f; l_run[r] = 0.f; }
    int srow = sbase + g * 4;   // + r

    for (int tt = 0; tt < S / 64; ++tt) {
        int t0 = tt * 64;
        __syncthreads();   // prev tile's LDS reads done
        {
            int row = tid >> 2, ch = tid & 3;
            const short* kp = QKV + (size_t)(b * S + t0 + row) * LD + 512 + h * 64 + ch * 16;
            short8 k0v = *reinterpret_cast<const short8*>(kp);
            short8 k1v = *reinterpret_cast<const short8*>(kp + 8);
            *reinterpret_cast<short8*>(&Kl[row][ch * 16]) = k0v;
            *reinterpret_cast<short8*>(&Kl[row][ch * 16 + 8]) = k1v;
            const short* vp = QKV + (size_t)(b * S + t0 + row) * LD + 1024 + h * 64 + ch * 16;
            short8 v0 = *reinterpret_cast<const short8*>(vp);
            short8 v1 = *reinterpret_cast<const short8*>(vp + 8);
#pragma unroll
            for (int j = 0; j < 8; ++j) Vt[ch * 16 + j][row] = v0[j];
#pragma unroll
            for (int j = 0; j < 8; ++j) Vt[ch * 16 + 8 + j][row] = v1[j];
        }
        __syncthreads();

        // S_tile = Q . K^T  (B-layout: col = lane&15 -> t, k contiguous)
        f32x4 sacc[4];
#pragma unroll
        for (int ni = 0; ni < 4; ++ni) {
            sacc[ni] = (f32x4){0.f, 0.f, 0.f, 0.f};
            short8 kb0 = *reinterpret_cast<const short8*>(&Kl[ni * 16 + c][g * 8]);
            short8 kb1 = *reinterpret_cast<const short8*>(&Kl[ni * 16 + c][32 + g * 8]);
            sacc[ni] = __builtin_amdgcn_mfma_f32_16x16x32_bf16(q0, kb0, sacc[ni], 0, 0, 0);
            sacc[ni] = __builtin_amdgcn_mfma_f32_16x16x32_bf16(q1, kb1, sacc[ni], 0, 0, 0);
        }

        // heatmap write (unmasked)
#pragma unroll
        for (int ni = 0; ni < 4; ++ni)
#pragma unroll
            for (int r = 0; r < 4; ++r)
                heat[((size_t)hb * S + sbase + g * 4 + r) * S + t0 + ni * 16 + c] = sacc[ni][r];

        bool active = (t0 <= sbase + 15);
        if (active) {
            float mt[4] = {-1e30f, -1e30f, -1e30f, -1e30f};
#pragma unroll
            for (int ni = 0; ni < 4; ++ni) {
                int t = t0 + ni * 16 + c;
#pragma unroll
                for (int r = 0; r < 4; ++r) {
                    float v = (t <= srow + r) ? sacc[ni][r] : -1e30f;
                    sacc[ni][r] = v;
                    mt[r] = fmaxf(mt[r], v);
                }
            }
#pragma unroll
            for (int off = 1; off < 16; off <<= 1)
#pragma unroll
                for (int r = 0; r < 4; ++r)
                    mt[r] = fmaxf(mt[r], __shfl_xor(mt[r], off));

            float scale[4], psum[4];
#pragma unroll
            for (int r = 0; r < 4; ++r) {
                float mn = fmaxf(m_run[r], mt[r]);
                scale[r] = __expf(m_run[r] - mn);
                m_run[r] = mn;
                psum[r] = 0.f;
            }
#pragma unroll
            for (int ni = 0; ni < 4; ++ni)
#pragma unroll
                for (int r = 0; r < 4; ++r) {
                    float p = __expf(sacc[ni][r] - m_run[r]);
                    sacc[ni][r] = p;
                    psum[r] += p;
                }
#pragma unroll
            for (int off = 1; off < 16; off <<= 1)
#pragma unroll
                for (int r = 0; r < 4; ++r)
                    psum[r] += __shfl_xor(psum[r], off);
#pragma unroll
            for (int r = 0; r < 4; ++r)
                l_run[r] = l_run[r] * scale[r] + psum[r];
#pragma unroll
            for (int ni = 0; ni < 4; ++ni)
#pragma unroll
                for (int r = 0; r < 4; ++r)
                    o[ni][r] *= scale[r];
            // write P (bf16, [s][t] layout so PV A-frags are contiguous)
#pragma unroll
            for (int ni = 0; ni < 4; ++ni)
#pragma unroll
                for (int r = 0; r < 4; ++r)
                    Pl[wid][g * 4 + r][ni * 16 + c] = f2bf(sacc[ni][r]);
        }
        __syncthreads();   // P visible (per-wave, but barrier keeps structure uniform)

        if (active) {
            short8 pa0 = *reinterpret_cast<const short8*>(&Pl[wid][c][g * 8]);
            short8 pa1 = *reinterpret_cast<const short8*>(&Pl[wid][c][32 + g * 8]);
#pragma unroll
            for (int ni = 0; ni < 4; ++ni) {
                short8 vb0 = *reinterpret_cast<const short8*>(&Vt[ni * 16 + c][g * 8]);
                short8 vb1 = *reinterpret_cast<const short8*>(&Vt[ni * 16 + c][32 + g * 8]);
                o[ni] = __builtin_amdgcn_mfma_f32_16x16x32_bf16(pa0, vb0, o[ni], 0, 0, 0);
                o[ni] = __builtin_amdgcn_mfma_f32_16x16x32_bf16(pa1, vb1, o[ni], 0, 0, 0);
            }
        }
    }

#pragma unroll
    for (int ni = 0; ni < 4; ++ni)
#pragma unroll
        for (int r = 0; r < 4; ++r) {
            float v = o[ni][r] / l_run[r];
            wv[(size_t)(b * S + sbase + g * 4 + r) * 512 + h * 64 + ni * 16 + c] = f2bf(v);
        }
}

// ---------------------------------------------------------------------------
// LayerNorm over last dim 512; optional secondary bf16 output.
// ---------------------------------------------------------------------------
__device__ __forceinline__ float block_sum256(float v, float* sm) {
#pragma unroll
    for (int off = 32; off; off >>= 1) v += __shfl_down(v, off);
    __syncthreads();
    if ((threadIdx.x & 63) == 0) sm[threadIdx.x >> 6] = v;
    __syncthreads();
    return sm[0] + sm[1] + sm[2] + sm[3];
}

__global__ __launch_bounds__(256) void ln_kernel(
    const float* __restrict__ in, const float* __restrict__ g,
    const float* __restrict__ bta, float* __restrict__ outf,
    short* __restrict__ outb)
{
    __shared__ float sm[4];
    int row = blockIdx.x, tid = threadIdx.x;
    const float* r = in + (size_t)row * 512;
    float v0 = r[tid], v1 = r[tid + 256];
    float mu = block_sum256(v0 + v1, sm) * (1.f / 512.f);
    float d0 = v0 - mu, d1 = v1 - mu;
    float var = block_sum256(d0 * d0 + d1 * d1, sm) * (1.f / 512.f);
    float rs = rsqrtf(var + 1e-5f);
    float o0 = d0 * rs * g[tid] + bta[tid];
    float o1 = d1 * rs * g[tid + 256] + bta[tid + 256];
    outf[(size_t)row * 512 + tid]       = o0;
    outf[(size_t)row * 512 + tid + 256] = o1;
    if (outb) {
        outb[(size_t)row * 512 + tid]       = f2bf(o0);
        outb[(size_t)row * 512 + tid + 256] = f2bf(o1);
    }
}

// ---------------------------------------------------------------------------
extern "C" void kernel_launch(void* const* d_in, const int* in_sizes, int n_in,
                              void* d_out, int out_size, void* d_ws, size_t ws_size,
                              hipStream_t stream)
{
    const float* x    = (const float*)d_in[0];
    const float* Wq   = (const float*)d_in[1];
    const float* bq   = (const float*)d_in[2];
    const float* Wk   = (const float*)d_in[3];
    const float* bk   = (const float*)d_in[4];
    const float* Wv   = (const float*)d_in[5];
    const float* bv   = (const float*)d_in[6];
    const float* Wo   = (const float*)d_in[7];
    const float* bo   = (const float*)d_in[8];
    const float* W1   = (const float*)d_in[9];
    const float* b1   = (const float*)d_in[10];
    const float* W2   = (const float*)d_in[11];
    const float* b2   = (const float*)d_in[12];
    const float* ln1g = (const float*)d_in[13];
    const float* ln1b = (const float*)d_in[14];
    const float* ln2g = (const float*)d_in[15];
    const float* ln2b = (const float*)d_in[16];

    const int S = 2048, D = 512, T = 4096, HD = 2048, HB = 16;

    char* w = (char*)d_ws;
    short* xb     = (short*)(w);                     // 4096x512 bf16
    short* QKVb   = (short*)(w + 4194304);           // 4096x1536 bf16
    short* wvb    = (short*)(w + 16777216);          // 4096x512 bf16
    float* tmpf   = (float*)(w + 20971520);          // 4096x512 f32
    float* x1f    = (float*)(w + 29360128);          // 4096x512 f32
    short* x1b    = (short*)(w + 37748736);          // 4096x512 bf16
    short* Wqkv_t = (short*)(w + 41943040);          // 1536x512 bf16
    short* Wo_t   = (short*)(w + 43515904);          // 512x512 bf16
    short* W1_t   = (short*)(w + 44040192);          // 2048x512 bf16
    short* W2_t   = (short*)(w + 46137344);          // 512x2048 bf16
    float* qbias  = (float*)(w + 48234496);          // 1536 f32
    short* hidb   = (short*)(w);                     // 4096x2048 bf16 (aliases xb+QKVb, dead by then)

    float* out_x2 = (float*)d_out;
    float* heat   = out_x2 + (size_t)T * D;

    // conversions
    convert_bf16_kernel<<<dim3((T * D) / 1024), 256, 0, stream>>>(x, xb, T * D);
    pack_bias_kernel<<<dim3(6), 256, 0, stream>>>(bq, bk, bv, qbias);
    transpose_convert_kernel<<<dim3(16, 16), 256, 0, stream>>>(Wq, Wqkv_t, 512, 512);
    transpose_convert_kernel<<<dim3(16, 16), 256, 0, stream>>>(Wk, Wqkv_t + 512 * 512, 512, 512);
    transpose_convert_kernel<<<dim3(16, 16), 256, 0, stream>>>(Wv, Wqkv_t + 1024 * 512, 512, 512);
    transpose_convert_kernel<<<dim3(16, 16), 256, 0, stream>>>(Wo, Wo_t, 512, 512);
    transpose_convert_kernel<<<dim3(16, 64), 256, 0, stream>>>(W1, W1_t, 512, 2048);
    transpose_convert_kernel<<<dim3(64, 16), 256, 0, stream>>>(W2, W2_t, 2048, 512);

    // QKV projection (combined, N=1536)
    gemm_mfma<4><<<dim3(32, 12), 256, 0, stream>>>(
        xb, 512, Wqkv_t, 512, qbias, nullptr, nullptr, QKVb, T, 1536, 512, 0);

    // fused attention + heatmap
    attn_kernel<<<dim3(HB, S / 64), 256, 0, stream>>>(QKVb, heat, wvb);

    // Wo projection + residual
    gemm_mfma<2><<<dim3(64, 4), 256, 0, stream>>>(
        wvb, 512, Wo_t, 512, bo, x, tmpf, nullptr, T, 512, 512, 0);
    ln_kernel<<<dim3(T), 256, 0, stream>>>(tmpf, ln1g, ln1b, x1f, x1b);

    // FFN
    gemm_mfma<4><<<dim3(32, 16), 256, 0, stream>>>(
        x1b, 512, W1_t, 512, b1, nullptr, nullptr, hidb, T, HD, 512, 1);
    gemm_mfma<2><<<dim3(64, 4), 256, 0, stream>>>(
        hidb, 2048, W2_t, 2048, b2, x1f, tmpf, nullptr, T, 512, 2048, 0);
    ln_kernel<<<dim3(T), 256, 0, stream>>>(tmpf, ln2g, ln2b, out_x2, nullptr);
}

// Round 4
// 262.020 us; speedup vs baseline: 4.8750x; 1.1505x over previous
//
#include <hip/hip_runtime.h>
#include <math.h>

typedef __attribute__((ext_vector_type(8))) short short8;
typedef __attribute__((ext_vector_type(4))) float f32x4;

__device__ __forceinline__ short f2bf(float f) {
    union { float f; unsigned u; } v; v.f = f;
    unsigned r = v.u + 0x7fff + ((v.u >> 16) & 1);
    return (short)(r >> 16);
}

// async global->LDS, 16B per lane; lds base must be wave-uniform.
__device__ __forceinline__ void gload16(const short* g, short* l) {
    __builtin_amdgcn_global_load_lds(
        (const __attribute__((address_space(1))) unsigned int*)g,
        (__attribute__((address_space(3))) unsigned int*)l,
        16, 0, 0);
}

// ---------------------------------------------------------------------------
// prep: x->bf16 (blocks 0..2047), weight transposes (2048..5119), bias pack.
// ---------------------------------------------------------------------------
__global__ __launch_bounds__(256) void prep_kernel(
    const float* __restrict__ x, short* __restrict__ xb,
    const float* __restrict__ Wq, const float* __restrict__ Wk,
    const float* __restrict__ Wv, const float* __restrict__ Wo,
    const float* __restrict__ W1, const float* __restrict__ W2,
    short* __restrict__ Wqkv_t, short* __restrict__ Wo_t,
    short* __restrict__ W1_t, short* __restrict__ W2_t,
    const float* __restrict__ bq, const float* __restrict__ bk,
    const float* __restrict__ bv, float* __restrict__ qbias)
{
    int bid = blockIdx.x;
    if (bid < 2048) {
        int i = (bid * 256 + threadIdx.x) * 4;
        float4 v = *reinterpret_cast<const float4*>(&x[i]);
        short4 o;
        o.x = f2bf(v.x); o.y = f2bf(v.y); o.z = f2bf(v.z); o.w = f2bf(v.w);
        *reinterpret_cast<short4*>(&xb[i]) = o;
        return;
    }
    if (bid < 5120) {
        int t = bid - 2048;
        const float* W; short* Wt; int K, N, nbx, loc;
        if (t < 1024) {
            int j = t >> 8; loc = t & 255; K = 512; N = 512; nbx = 16;
            W  = (j == 0) ? Wq : (j == 1) ? Wk : (j == 2) ? Wv : Wo;
            Wt = (j == 0) ? Wqkv_t : (j == 1) ? Wqkv_t + 512 * 512
               : (j == 2) ? Wqkv_t + 1024 * 512 : Wo_t;
        } else if (t < 2048) {
            loc = t - 1024; W = W1; Wt = W1_t; K = 512; N = 2048; nbx = 16;
        } else {
            loc = t - 2048; W = W2; Wt = W2_t; K = 2048; N = 512; nbx = 64;
        }
        int k0 = (loc % nbx) * 32, n0 = (loc / nbx) * 32;
        __shared__ float tl[32][33];
        int tx = threadIdx.x & 31, ty = threadIdx.x >> 5;
#pragma unroll
        for (int r = ty; r < 32; r += 8)
            tl[r][tx] = W[(size_t)(k0 + r) * N + n0 + tx];
        __syncthreads();
#pragma unroll
        for (int r = ty; r < 32; r += 8)
            Wt[(size_t)(n0 + r) * K + k0 + tx] = f2bf(tl[tx][r]);
        return;
    }
    {
        int i = (bid - 5120) * 256 + threadIdx.x;
        if (i < 1536)
            qbias[i] = (i < 512) ? bq[i] : (i < 1024 ? bk[i - 512] : bv[i - 1024]);
    }
}

// ---------------------------------------------------------------------------
// bf16 MFMA GEMM, m97-style staging: BK=64, global_load_lds width 16,
// linear LDS. BM = MI*32, BN = 128, 4 waves.
// ---------------------------------------------------------------------------
template<int MI>
__global__ __launch_bounds__(256) void gemm2(
    const short* __restrict__ A, int lda,
    const short* __restrict__ Bt, int ldb,
    const float* __restrict__ bias,
    const float* __restrict__ resid,
    float* __restrict__ Cf, short* __restrict__ Cb,
    int N, int K, int relu)
{
    constexpr int BM = MI * 32;
    __shared__ short Ash[BM * 64];
    __shared__ short Bsh[128 * 64];
    int tid = threadIdx.x;
    int wid = tid >> 6, lane = tid & 63;
    int g = lane >> 4, c = lane & 15;
    int wm = wid >> 1, wn = wid & 1;
    size_t m0 = (size_t)blockIdx.x * BM;
    size_t n0 = (size_t)blockIdx.y * 128;
    int lrow = lane >> 3;          // 0..7
    int lcol = (lane & 7) * 8;     // shorts (16B granule)

    f32x4 acc[MI][4];
#pragma unroll
    for (int i = 0; i < MI; ++i)
#pragma unroll
        for (int j = 0; j < 4; ++j)
            acc[i][j] = (f32x4){0.f, 0.f, 0.f, 0.f};

    for (int k0 = 0; k0 < K; k0 += 64) {
        __syncthreads();
#pragma unroll
        for (int i = 0; i < MI; ++i) {              // A: BM/8 chunks of 1KB
            int chunk = wid * MI + i;
            int row = chunk * 8 + lrow;
            gload16(A + (m0 + row) * lda + k0 + lcol, Ash + chunk * 512);
        }
#pragma unroll
        for (int i = 0; i < 4; ++i) {               // B: 16 chunks
            int chunk = wid * 4 + i;
            int row = chunk * 8 + lrow;
            gload16(Bt + (n0 + row) * ldb + k0 + lcol, Bsh + chunk * 512);
        }
        __syncthreads();

        short8 a[MI][2], b[4][2];
#pragma unroll
        for (int kc = 0; kc < 2; ++kc) {
#pragma unroll
            for (int mi = 0; mi < MI; ++mi)
                a[mi][kc] = *(const short8*)&Ash[(wm * MI * 16 + mi * 16 + c) * 64 + kc * 32 + g * 8];
#pragma unroll
            for (int ni = 0; ni < 4; ++ni)
                b[ni][kc] = *(const short8*)&Bsh[(wn * 64 + ni * 16 + c) * 64 + kc * 32 + g * 8];
        }
#pragma unroll
        for (int kc = 0; kc < 2; ++kc)
#pragma unroll
            for (int mi = 0; mi < MI; ++mi)
#pragma unroll
                for (int ni = 0; ni < 4; ++ni)
                    acc[mi][ni] = __builtin_amdgcn_mfma_f32_16x16x32_bf16(
                        a[mi][kc], b[ni][kc], acc[mi][ni], 0, 0, 0);
    }

#pragma unroll
    for (int mi = 0; mi < MI; ++mi)
#pragma unroll
        for (int ni = 0; ni < 4; ++ni)
#pragma unroll
            for (int r = 0; r < 4; ++r) {
                size_t m = m0 + wm * (MI * 16) + mi * 16 + g * 4 + r;
                size_t n = n0 + wn * 64 + ni * 16 + c;
                float v = acc[mi][ni][r];
                if (bias)  v += bias[n];
                if (resid) v += resid[m * N + n];
                if (relu)  v = fmaxf(v, 0.f);
                if (Cf) Cf[m * N + n] = v;
                if (Cb) Cb[m * N + n] = f2bf(v);
            }
}

// ---------------------------------------------------------------------------
// Fused flash attention + heatmap. K-fragments direct from global (L2-hot),
// V double-buffered in LDS (causal tiles only), score-only phase barrier-free.
// grid (32, 16): x = s-block pair index (work balance), y = hb.
// ---------------------------------------------------------------------------
__global__ __launch_bounds__(256) void attn_kernel(
    const short* __restrict__ QKV,
    float* __restrict__ heat,
    short* __restrict__ wv)
{
    constexpr int S = 2048;
    constexpr int LD = 1536;
    __shared__ short Vt[2][64][72];    // [buf][v][t]
    __shared__ short Pl[4][16][72];    // per-wave P, [s][t]

    int tid = threadIdx.x;
    int wid = tid >> 6, lane = tid & 63;
    int g = lane >> 4, c = lane & 15;
    int hb = blockIdx.y, h = hb >> 1, b = hb & 1;
    int y = blockIdx.x;
    int by = (y & 1) ? (31 - (y >> 1)) : (y >> 1);   // pair (k, 31-k)
    int s0 = by * 64;
    int sbase = s0 + wid * 16;

    short8 q0, q1;
    {
        const short* qp = QKV + (size_t)(b * S + sbase + c) * LD + h * 64 + g * 8;
        q0 = *reinterpret_cast<const short8*>(qp);
        q1 = *reinterpret_cast<const short8*>(qp + 32);
    }

    f32x4 o[4];
    float m_run[4], l_run[4];
#pragma unroll
    for (int ni = 0; ni < 4; ++ni) o[ni] = (f32x4){0.f, 0.f, 0.f, 0.f};
#pragma unroll
    for (int r = 0; r < 4; ++r) { m_run[r] = -1e30f; l_run[r] = 0.f; }
    int srow = sbase + g * 4;

    auto loadK = [&](int tt, short8 dst[4][2]) {
        const short* kb = QKV + (size_t)(b * S + tt * 64) * LD + 512 + h * 64;
#pragma unroll
        for (int ni = 0; ni < 4; ++ni)
#pragma unroll
            for (int kc = 0; kc < 2; ++kc)
                dst[ni][kc] = *(const short8*)(kb + (size_t)(ni * 16 + c) * LD + kc * 32 + g * 8);
    };

    short8 kcur[4][2];
    loadK(0, kcur);

    // ---- causal phase: tiles 0..by, 1 barrier each ----
    for (int tt = 0; tt <= by; ++tt) {
        int t0 = tt * 64;
        {   // stage V into Vt[tt&1]
            int row = tid >> 2, ch = tid & 3;
            const short* vp = QKV + (size_t)(b * S + t0 + row) * LD + 1024 + h * 64 + ch * 16;
            short8 v0 = *reinterpret_cast<const short8*>(vp);
            short8 v1 = *reinterpret_cast<const short8*>(vp + 8);
#pragma unroll
            for (int j = 0; j < 8; ++j) Vt[tt & 1][ch * 16 + j][row] = v0[j];
#pragma unroll
            for (int j = 0; j < 8; ++j) Vt[tt & 1][ch * 16 + 8 + j][row] = v1[j];
        }
        __syncthreads();

        short8 knext[4][2];
        if (tt < 31) loadK(tt + 1, knext);

        f32x4 sacc[4];
#pragma unroll
        for (int ni = 0; ni < 4; ++ni) {
            sacc[ni] = (f32x4){0.f, 0.f, 0.f, 0.f};
            sacc[ni] = __builtin_amdgcn_mfma_f32_16x16x32_bf16(q0, kcur[ni][0], sacc[ni], 0, 0, 0);
            sacc[ni] = __builtin_amdgcn_mfma_f32_16x16x32_bf16(q1, kcur[ni][1], sacc[ni], 0, 0, 0);
        }
#pragma unroll
        for (int ni = 0; ni < 4; ++ni)
#pragma unroll
            for (int r = 0; r < 4; ++r)
                __builtin_nontemporal_store(sacc[ni][r],
                    &heat[((size_t)hb * S + sbase + g * 4 + r) * S + t0 + ni * 16 + c]);

        float mt[4] = {-1e30f, -1e30f, -1e30f, -1e30f};
#pragma unroll
        for (int ni = 0; ni < 4; ++ni) {
            int t = t0 + ni * 16 + c;
#pragma unroll
            for (int r = 0; r < 4; ++r) {
                float v = (t <= srow + r) ? sacc[ni][r] : -1e30f;
                sacc[ni][r] = v;
                mt[r] = fmaxf(mt[r], v);
            }
        }
#pragma unroll
        for (int off = 1; off < 16; off <<= 1)
#pragma unroll
            for (int r = 0; r < 4; ++r)
                mt[r] = fmaxf(mt[r], __shfl_xor(mt[r], off));

        float scale[4], psum[4];
#pragma unroll
        for (int r = 0; r < 4; ++r) {
            float mn = fmaxf(m_run[r], mt[r]);
            scale[r] = __expf(m_run[r] - mn);
            m_run[r] = mn;
            psum[r] = 0.f;
        }
#pragma unroll
        for (int ni = 0; ni < 4; ++ni)
#pragma unroll
            for (int r = 0; r < 4; ++r) {
                float p = __expf(sacc[ni][r] - m_run[r]);
                sacc[ni][r] = p;
                psum[r] += p;
            }
#pragma unroll
        for (int off = 1; off < 16; off <<= 1)
#pragma unroll
            for (int r = 0; r < 4; ++r)
                psum[r] += __shfl_xor(psum[r], off);
#pragma unroll
        for (int r = 0; r < 4; ++r)
            l_run[r] = l_run[r] * scale[r] + psum[r];
#pragma unroll
        for (int ni = 0; ni < 4; ++ni)
#pragma unroll
            for (int r = 0; r < 4; ++r)
                o[ni][r] *= scale[r];
#pragma unroll
        for (int ni = 0; ni < 4; ++ni)
#pragma unroll
            for (int r = 0; r < 4; ++r)
                Pl[wid][g * 4 + r][ni * 16 + c] = f2bf(sacc[ni][r]);

        short8 pa0 = *reinterpret_cast<const short8*>(&Pl[wid][c][g * 8]);
        short8 pa1 = *reinterpret_cast<const short8*>(&Pl[wid][c][32 + g * 8]);
#pragma unroll
        for (int ni = 0; ni < 4; ++ni) {
            short8 vb0 = *reinterpret_cast<const short8*>(&Vt[tt & 1][ni * 16 + c][g * 8]);
            short8 vb1 = *reinterpret_cast<const short8*>(&Vt[tt & 1][ni * 16 + c][32 + g * 8]);
            o[ni] = __builtin_amdgcn_mfma_f32_16x16x32_bf16(pa0, vb0, o[ni], 0, 0, 0);
            o[ni] = __builtin_amdgcn_mfma_f32_16x16x32_bf16(pa1, vb1, o[ni], 0, 0, 0);
        }
#pragma unroll
        for (int ni = 0; ni < 4; ++ni)
#pragma unroll
            for (int kc = 0; kc < 2; ++kc)
                kcur[ni][kc] = knext[ni][kc];
    }

    // ---- score-only phase: barrier-free ----
    for (int tt = by + 1; tt < 32; ++tt) {
        int t0 = tt * 64;
        short8 knext[4][2];
        if (tt < 31) loadK(tt + 1, knext);
        f32x4 sacc[4];
#pragma unroll
        for (int ni = 0; ni < 4; ++ni) {
            sacc[ni] = (f32x4){0.f, 0.f, 0.f, 0.f};
            sacc[ni] = __builtin_amdgcn_mfma_f32_16x16x32_bf16(q0, kcur[ni][0], sacc[ni], 0, 0, 0);
            sacc[ni] = __builtin_amdgcn_mfma_f32_16x16x32_bf16(q1, kcur[ni][1], sacc[ni], 0, 0, 0);
        }
#pragma unroll
        for (int ni = 0; ni < 4; ++ni)
#pragma unroll
            for (int r = 0; r < 4; ++r)
                __builtin_nontemporal_store(sacc[ni][r],
                    &heat[((size_t)hb * S + sbase + g * 4 + r) * S + t0 + ni * 16 + c]);
#pragma unroll
        for (int ni = 0; ni < 4; ++ni)
#pragma unroll
            for (int kc = 0; kc < 2; ++kc)
                kcur[ni][kc] = knext[ni][kc];
    }

#pragma unroll
    for (int ni = 0; ni < 4; ++ni)
#pragma unroll
        for (int r = 0; r < 4; ++r) {
            float v = o[ni][r] / l_run[r];
            wv[(size_t)(b * S + sbase + g * 4 + r) * 512 + h * 64 + ni * 16 + c] = f2bf(v);
        }
}

// ---------------------------------------------------------------------------
// LayerNorm over last dim 512; optional secondary bf16 output.
// ---------------------------------------------------------------------------
__device__ __forceinline__ float block_sum256(float v, float* sm) {
#pragma unroll
    for (int off = 32; off; off >>= 1) v += __shfl_down(v, off);
    __syncthreads();
    if ((threadIdx.x & 63) == 0) sm[threadIdx.x >> 6] = v;
    __syncthreads();
    return sm[0] + sm[1] + sm[2] + sm[3];
}

__global__ __launch_bounds__(256) void ln_kernel(
    const float* __restrict__ in, const float* __restrict__ g,
    const float* __restrict__ bta, float* __restrict__ outf,
    short* __restrict__ outb)
{
    __shared__ float sm[4];
    int row = blockIdx.x, tid = threadIdx.x;
    const float* r = in + (size_t)row * 512;
    float v0 = r[tid], v1 = r[tid + 256];
    float mu = block_sum256(v0 + v1, sm) * (1.f / 512.f);
    float d0 = v0 - mu, d1 = v1 - mu;
    float var = block_sum256(d0 * d0 + d1 * d1, sm) * (1.f / 512.f);
    float rs = rsqrtf(var + 1e-5f);
    float o0 = d0 * rs * g[tid] + bta[tid];
    float o1 = d1 * rs * g[tid + 256] + bta[tid + 256];
    outf[(size_t)row * 512 + tid]       = o0;
    outf[(size_t)row * 512 + tid + 256] = o1;
    if (outb) {
        outb[(size_t)row * 512 + tid]       = f2bf(o0);
        outb[(size_t)row * 512 + tid + 256] = f2bf(o1);
    }
}

// ---------------------------------------------------------------------------
extern "C" void kernel_launch(void* const* d_in, const int* in_sizes, int n_in,
                              void* d_out, int out_size, void* d_ws, size_t ws_size,
                              hipStream_t stream)
{
    const float* x    = (const float*)d_in[0];
    const float* Wq   = (const float*)d_in[1];
    const float* bq   = (const float*)d_in[2];
    const float* Wk   = (const float*)d_in[3];
    const float* bk   = (const float*)d_in[4];
    const float* Wv   = (const float*)d_in[5];
    const float* bv   = (const float*)d_in[6];
    const float* Wo   = (const float*)d_in[7];
    const float* bo   = (const float*)d_in[8];
    const float* W1   = (const float*)d_in[9];
    const float* b1   = (const float*)d_in[10];
    const float* W2   = (const float*)d_in[11];
    const float* b2   = (const float*)d_in[12];
    const float* ln1g = (const float*)d_in[13];
    const float* ln1b = (const float*)d_in[14];
    const float* ln2g = (const float*)d_in[15];
    const float* ln2b = (const float*)d_in[16];

    const int S = 2048, D = 512, T = 4096, HD = 2048;

    char* w = (char*)d_ws;
    short* xb     = (short*)(w);                     // 4096x512 bf16
    short* QKVb   = (short*)(w + 4194304);           // 4096x1536 bf16
    short* wvb    = (short*)(w + 16777216);          // 4096x512 bf16
    float* tmpf   = (float*)(w + 20971520);          // 4096x512 f32
    float* x1f    = (float*)(w + 29360128);          // 4096x512 f32
    short* x1b    = (short*)(w + 37748736);          // 4096x512 bf16
    short* Wqkv_t = (short*)(w + 41943040);          // 1536x512 bf16
    short* Wo_t   = (short*)(w + 43515904);          // 512x512 bf16
    short* W1_t   = (short*)(w + 44040192);          // 2048x512 bf16
    short* W2_t   = (short*)(w + 46137344);          // 512x2048 bf16
    float* qbias  = (float*)(w + 48234496);          // 1536 f32
    short* hidb   = (short*)(w);                     // 4096x2048 bf16 (aliases xb+QKVb)

    float* out_x2 = (float*)d_out;
    float* heat   = out_x2 + (size_t)T * D;

    prep_kernel<<<dim3(5126), 256, 0, stream>>>(
        x, xb, Wq, Wk, Wv, Wo, W1, W2,
        Wqkv_t, Wo_t, W1_t, W2_t, bq, bk, bv, qbias);

    gemm2<4><<<dim3(32, 12), 256, 0, stream>>>(
        xb, 512, Wqkv_t, 512, qbias, nullptr, nullptr, QKVb, 1536, 512, 0);

    attn_kernel<<<dim3(32, 16), 256, 0, stream>>>(QKVb, heat, wvb);

    gemm2<2><<<dim3(64, 4), 256, 0, stream>>>(
        wvb, 512, Wo_t, 512, bo, x, tmpf, nullptr, 512, 512, 0);
    ln_kernel<<<dim3(T), 256, 0, stream>>>(tmpf, ln1g, ln1b, x1f, x1b);

    gemm2<4><<<dim3(32, 16), 256, 0, stream>>>(
        x1b, 512, W1_t, 512, b1, nullptr, nullptr, hidb, HD, 512, 1);
    gemm2<2><<<dim3(64, 4), 256, 0, stream>>>(
        hidb, 2048, W2_t, 2048, b2, x1f, tmpf, nullptr, 512, 2048, 0);
    ln_kernel<<<dim3(T), 256, 0, stream>>>(tmpf, ln2g, ln2b, out_x2, nullptr);
}

// Round 5
// 230.780 us; speedup vs baseline: 5.5350x; 1.1354x over previous
//
#include <hip/hip_runtime.h>
#include <math.h>

typedef __attribute__((ext_vector_type(8))) short short8;
typedef __attribute__((ext_vector_type(4))) float f32x4;

__device__ __forceinline__ short f2bf(float f) {
    union { float f; unsigned u; } v; v.f = f;
    unsigned r = v.u + 0x7fff + ((v.u >> 16) & 1);
    return (short)(r >> 16);
}

// async global->LDS, 16B per lane; lds base must be wave-uniform.
__device__ __forceinline__ void gload16(const short* g, short* l) {
    __builtin_amdgcn_global_load_lds(
        (const __attribute__((address_space(1))) unsigned int*)g,
        (__attribute__((address_space(3))) unsigned int*)l,
        16, 0, 0);
}

// ---------------------------------------------------------------------------
// prep: x->bf16 (blocks 0..2047), weight transposes (2048..5119), bias pack.
// ---------------------------------------------------------------------------
__global__ __launch_bounds__(256) void prep_kernel(
    const float* __restrict__ x, short* __restrict__ xb,
    const float* __restrict__ Wq, const float* __restrict__ Wk,
    const float* __restrict__ Wv, const float* __restrict__ Wo,
    const float* __restrict__ W1, const float* __restrict__ W2,
    short* __restrict__ Wqkv_t, short* __restrict__ Wo_t,
    short* __restrict__ W1_t, short* __restrict__ W2_t,
    const float* __restrict__ bq, const float* __restrict__ bk,
    const float* __restrict__ bv, float* __restrict__ qbias)
{
    int bid = blockIdx.x;
    if (bid < 2048) {
        int i = (bid * 256 + threadIdx.x) * 4;
        float4 v = *reinterpret_cast<const float4*>(&x[i]);
        short4 o;
        o.x = f2bf(v.x); o.y = f2bf(v.y); o.z = f2bf(v.z); o.w = f2bf(v.w);
        *reinterpret_cast<short4*>(&xb[i]) = o;
        return;
    }
    if (bid < 5120) {
        int t = bid - 2048;
        const float* W; short* Wt; int K, N, nbx, loc;
        if (t < 1024) {
            int j = t >> 8; loc = t & 255; K = 512; N = 512; nbx = 16;
            W  = (j == 0) ? Wq : (j == 1) ? Wk : (j == 2) ? Wv : Wo;
            Wt = (j == 0) ? Wqkv_t : (j == 1) ? Wqkv_t + 512 * 512
               : (j == 2) ? Wqkv_t + 1024 * 512 : Wo_t;
        } else if (t < 2048) {
            loc = t - 1024; W = W1; Wt = W1_t; K = 512; N = 2048; nbx = 16;
        } else {
            loc = t - 2048; W = W2; Wt = W2_t; K = 2048; N = 512; nbx = 64;
        }
        int k0 = (loc % nbx) * 32, n0 = (loc / nbx) * 32;
        __shared__ float tl[32][33];
        int tx = threadIdx.x & 31, ty = threadIdx.x >> 5;
#pragma unroll
        for (int r = ty; r < 32; r += 8)
            tl[r][tx] = W[(size_t)(k0 + r) * N + n0 + tx];
        __syncthreads();
#pragma unroll
        for (int r = ty; r < 32; r += 8)
            Wt[(size_t)(n0 + r) * K + k0 + tx] = f2bf(tl[tx][r]);
        return;
    }
    {
        int i = (bid - 5120) * 256 + threadIdx.x;
        if (i < 1536)
            qbias[i] = (i < 512) ? bq[i] : (i < 1024 ? bk[i - 512] : bv[i - 1024]);
    }
}

// ---------------------------------------------------------------------------
// bf16 MFMA GEMM. BM = MI*32, BN = NI*32, BK = 64, 4 waves (2x2).
// global_load_lds width-16 staging, linear LDS.
// ---------------------------------------------------------------------------
template<int MI, int NI>
__global__ __launch_bounds__(256) void gemm2(
    const short* __restrict__ A, int lda,
    const short* __restrict__ Bt, int ldb,
    const float* __restrict__ bias,
    const float* __restrict__ resid,
    float* __restrict__ Cf, short* __restrict__ Cb,
    int N, int K, int relu)
{
    constexpr int BM = MI * 32;
    constexpr int BN = NI * 32;
    __shared__ short Ash[BM * 64];
    __shared__ short Bsh[BN * 64];
    int tid = threadIdx.x;
    int wid = tid >> 6, lane = tid & 63;
    int g = lane >> 4, c = lane & 15;
    int wm = wid >> 1, wn = wid & 1;
    size_t m0 = (size_t)blockIdx.x * BM;
    size_t n0 = (size_t)blockIdx.y * BN;
    int lrow = lane >> 3;          // 0..7
    int lcol = (lane & 7) * 8;     // shorts (16B granule)

    f32x4 acc[MI][NI];
#pragma unroll
    for (int i = 0; i < MI; ++i)
#pragma unroll
        for (int j = 0; j < NI; ++j)
            acc[i][j] = (f32x4){0.f, 0.f, 0.f, 0.f};

    for (int k0 = 0; k0 < K; k0 += 64) {
        __syncthreads();
#pragma unroll
        for (int i = 0; i < MI; ++i) {              // A: BM/8 chunks of 1KB
            int chunk = wid * MI + i;
            int row = chunk * 8 + lrow;
            gload16(A + (m0 + row) * lda + k0 + lcol, Ash + chunk * 512);
        }
#pragma unroll
        for (int i = 0; i < NI; ++i) {              // B: BN/8 chunks
            int chunk = wid * NI + i;
            int row = chunk * 8 + lrow;
            gload16(Bt + (n0 + row) * ldb + k0 + lcol, Bsh + chunk * 512);
        }
        __syncthreads();

        short8 a[MI][2], b[NI][2];
#pragma unroll
        for (int kc = 0; kc < 2; ++kc) {
#pragma unroll
            for (int mi = 0; mi < MI; ++mi)
                a[mi][kc] = *(const short8*)&Ash[(wm * MI * 16 + mi * 16 + c) * 64 + kc * 32 + g * 8];
#pragma unroll
            for (int ni = 0; ni < NI; ++ni)
                b[ni][kc] = *(const short8*)&Bsh[(wn * NI * 16 + ni * 16 + c) * 64 + kc * 32 + g * 8];
        }
#pragma unroll
        for (int kc = 0; kc < 2; ++kc)
#pragma unroll
            for (int mi = 0; mi < MI; ++mi)
#pragma unroll
                for (int ni = 0; ni < NI; ++ni)
                    acc[mi][ni] = __builtin_amdgcn_mfma_f32_16x16x32_bf16(
                        a[mi][kc], b[ni][kc], acc[mi][ni], 0, 0, 0);
    }

#pragma unroll
    for (int mi = 0; mi < MI; ++mi)
#pragma unroll
        for (int ni = 0; ni < NI; ++ni)
#pragma unroll
            for (int r = 0; r < 4; ++r) {
                size_t m = m0 + wm * (MI * 16) + mi * 16 + g * 4 + r;
                size_t n = n0 + wn * (NI * 16) + ni * 16 + c;
                float v = acc[mi][ni][r];
                if (bias)  v += bias[n];
                if (resid) v += resid[m * N + n];
                if (relu)  v = fmaxf(v, 0.f);
                if (Cf) Cf[m * N + n] = v;
                if (Cb) Cb[m * N + n] = f2bf(v);
            }
}

// ---------------------------------------------------------------------------
// Fused flash attention + heatmap, swapped-operand QK^T (S^T in registers:
// lane owns s-row = lane&15, 16 t-values register-local).
// K-fragments direct from global (L2-hot), V double-buffered in LDS (causal
// tiles only), score-only phase barrier-free. grid (32, 16).
// ---------------------------------------------------------------------------
__global__ __launch_bounds__(256) void attn_kernel(
    const short* __restrict__ QKV,
    float* __restrict__ heat,
    short* __restrict__ wv)
{
    constexpr int S = 2048;
    constexpr int LD = 1536;
    __shared__ short Vt[2][64][72];    // [buf][v][t]
    __shared__ short Pl[4][16][72];    // per-wave P, [s][t]

    int tid = threadIdx.x;
    int wid = tid >> 6, lane = tid & 63;
    int g = lane >> 4, c = lane & 15;
    int g4 = g * 4;
    int hb = blockIdx.y, h = hb >> 1, b = hb & 1;
    int y = blockIdx.x;
    int by = (y & 1) ? (31 - (y >> 1)) : (y >> 1);   // pair (k, 31-k)
    int s0 = by * 64;
    int sbase = s0 + wid * 16;
    int sglob = sbase + c;                 // this lane's s-row

    short8 q0, q1;   // Q as B-operand: col = c -> s-row sbase+c, k = g*8+i
    {
        const short* qp = QKV + (size_t)(b * S + sbase + c) * LD + h * 64 + g * 8;
        q0 = *reinterpret_cast<const short8*>(qp);
        q1 = *reinterpret_cast<const short8*>(qp + 32);
    }

    f32x4 o[4];
    float m_run = -1e30f, l_run = 0.f;
#pragma unroll
    for (int ni = 0; ni < 4; ++ni) o[ni] = (f32x4){0.f, 0.f, 0.f, 0.f};

    // K as A-operand: row = c -> t-row ni*16+c, k = kc*32+g*8+i
    auto loadK = [&](int tt, short8 dst[4][2]) {
        const short* kb = QKV + (size_t)(b * S + tt * 64) * LD + 512 + h * 64;
#pragma unroll
        for (int ni = 0; ni < 4; ++ni)
#pragma unroll
            for (int kc = 0; kc < 2; ++kc)
                dst[ni][kc] = *(const short8*)(kb + (size_t)(ni * 16 + c) * LD + kc * 32 + g * 8);
    };

    short8 kcur[4][2];
    loadK(0, kcur);

    // ---- causal phase: tiles 0..by ----
    for (int tt = 0; tt <= by; ++tt) {
        int t0 = tt * 64;
        {   // stage V into Vt[tt&1]
            int row = tid >> 2, ch = tid & 3;
            const short* vp = QKV + (size_t)(b * S + t0 + row) * LD + 1024 + h * 64 + ch * 16;
            short8 v0 = *reinterpret_cast<const short8*>(vp);
            short8 v1 = *reinterpret_cast<const short8*>(vp + 8);
#pragma unroll
            for (int j = 0; j < 8; ++j) Vt[tt & 1][ch * 16 + j][row] = v0[j];
#pragma unroll
            for (int j = 0; j < 8; ++j) Vt[tt & 1][ch * 16 + 8 + j][row] = v1[j];
        }
        __syncthreads();

        short8 knext[4][2];
        if (tt < 31) loadK(tt + 1, knext);

        // S^T tile: lane holds s = sglob, t = t0 + ni*16 + g*4 + r
        f32x4 sacc[4];
#pragma unroll
        for (int ni = 0; ni < 4; ++ni) {
            sacc[ni] = (f32x4){0.f, 0.f, 0.f, 0.f};
            sacc[ni] = __builtin_amdgcn_mfma_f32_16x16x32_bf16(kcur[ni][0], q0, sacc[ni], 0, 0, 0);
            sacc[ni] = __builtin_amdgcn_mfma_f32_16x16x32_bf16(kcur[ni][1], q1, sacc[ni], 0, 0, 0);
        }
        // heatmap: 4 x f32x4 nontemporal stores (16B/lane each)
#pragma unroll
        for (int ni = 0; ni < 4; ++ni)
            __builtin_nontemporal_store(sacc[ni],
                (f32x4*)&heat[((size_t)hb * S + sglob) * S + t0 + ni * 16 + g4]);

        // mask + lane-local row max
        float tm = -1e30f;
#pragma unroll
        for (int ni = 0; ni < 4; ++ni) {
#pragma unroll
            for (int r = 0; r < 4; ++r) {
                int t = t0 + ni * 16 + g4 + r;
                float v = (t <= sglob) ? sacc[ni][r] : -1e30f;
                sacc[ni][r] = v;
                tm = fmaxf(tm, v);
            }
        }
        tm = fmaxf(tm, __shfl_xor(tm, 16));
        tm = fmaxf(tm, __shfl_xor(tm, 32));

        float mn = fmaxf(m_run, tm);
        float sc = __expf(m_run - mn);
        m_run = mn;
        float ps = 0.f;
#pragma unroll
        for (int ni = 0; ni < 4; ++ni)
#pragma unroll
            for (int r = 0; r < 4; ++r) {
                float p = __expf(sacc[ni][r] - mn);
                sacc[ni][r] = p;
                ps += p;
            }
        ps += __shfl_xor(ps, 16);
        ps += __shfl_xor(ps, 32);
        l_run = l_run * sc + ps;

        // rescale o: o rows are s = sbase + g*4 + r -> need sc from lane g*4+r
        float scr[4];
#pragma unroll
        for (int r = 0; r < 4; ++r) scr[r] = __shfl(sc, g4 + r, 64);
#pragma unroll
        for (int ni = 0; ni < 4; ++ni)
#pragma unroll
            for (int r = 0; r < 4; ++r)
                o[ni][r] *= scr[r];

        // P staging: lane owns row s=c, 4 consecutive t per frag -> b64 writes
#pragma unroll
        for (int ni = 0; ni < 4; ++ni) {
            short4 pw;
            pw.x = f2bf(sacc[ni][0]); pw.y = f2bf(sacc[ni][1]);
            pw.z = f2bf(sacc[ni][2]); pw.w = f2bf(sacc[ni][3]);
            *reinterpret_cast<short4*>(&Pl[wid][c][ni * 16 + g4]) = pw;
        }

        short8 pa0 = *reinterpret_cast<const short8*>(&Pl[wid][c][g * 8]);
        short8 pa1 = *reinterpret_cast<const short8*>(&Pl[wid][c][32 + g * 8]);
#pragma unroll
        for (int ni = 0; ni < 4; ++ni) {
            short8 vb0 = *reinterpret_cast<const short8*>(&Vt[tt & 1][ni * 16 + c][g * 8]);
            short8 vb1 = *reinterpret_cast<const short8*>(&Vt[tt & 1][ni * 16 + c][32 + g * 8]);
            o[ni] = __builtin_amdgcn_mfma_f32_16x16x32_bf16(pa0, vb0, o[ni], 0, 0, 0);
            o[ni] = __builtin_amdgcn_mfma_f32_16x16x32_bf16(pa1, vb1, o[ni], 0, 0, 0);
        }
#pragma unroll
        for (int ni = 0; ni < 4; ++ni)
#pragma unroll
            for (int kc = 0; kc < 2; ++kc)
                kcur[ni][kc] = knext[ni][kc];
    }

    // ---- score-only phase: barrier-free ----
    for (int tt = by + 1; tt < 32; ++tt) {
        int t0 = tt * 64;
        short8 knext[4][2];
        if (tt < 31) loadK(tt + 1, knext);
        f32x4 sacc[4];
#pragma unroll
        for (int ni = 0; ni < 4; ++ni) {
            sacc[ni] = (f32x4){0.f, 0.f, 0.f, 0.f};
            sacc[ni] = __builtin_amdgcn_mfma_f32_16x16x32_bf16(kcur[ni][0], q0, sacc[ni], 0, 0, 0);
            sacc[ni] = __builtin_amdgcn_mfma_f32_16x16x32_bf16(kcur[ni][1], q1, sacc[ni], 0, 0, 0);
        }
#pragma unroll
        for (int ni = 0; ni < 4; ++ni)
            __builtin_nontemporal_store(sacc[ni],
                (f32x4*)&heat[((size_t)hb * S + sglob) * S + t0 + ni * 16 + g4]);
#pragma unroll
        for (int ni = 0; ni < 4; ++ni)
#pragma unroll
            for (int kc = 0; kc < 2; ++kc)
                kcur[ni][kc] = knext[ni][kc];
    }

    // final: o rows s = sbase + g*4 + r need l from lane g*4+r
    float linv[4];
#pragma unroll
    for (int r = 0; r < 4; ++r) linv[r] = 1.0f / __shfl(l_run, g4 + r, 64);
#pragma unroll
    for (int ni = 0; ni < 4; ++ni)
#pragma unroll
        for (int r = 0; r < 4; ++r) {
            float v = o[ni][r] * linv[r];
            wv[(size_t)(b * S + sbase + g4 + r) * 512 + h * 64 + ni * 16 + c] = f2bf(v);
        }
}

// ---------------------------------------------------------------------------
// LayerNorm over last dim 512; optional secondary bf16 output.
// ---------------------------------------------------------------------------
__device__ __forceinline__ float block_sum256(float v, float* sm) {
#pragma unroll
    for (int off = 32; off; off >>= 1) v += __shfl_down(v, off);
    __syncthreads();
    if ((threadIdx.x & 63) == 0) sm[threadIdx.x >> 6] = v;
    __syncthreads();
    return sm[0] + sm[1] + sm[2] + sm[3];
}

__global__ __launch_bounds__(256) void ln_kernel(
    const float* __restrict__ in, const float* __restrict__ g,
    const float* __restrict__ bta, float* __restrict__ outf,
    short* __restrict__ outb)
{
    __shared__ float sm[4];
    int row = blockIdx.x, tid = threadIdx.x;
    const float* r = in + (size_t)row * 512;
    float v0 = r[tid], v1 = r[tid + 256];
    float mu = block_sum256(v0 + v1, sm) * (1.f / 512.f);
    float d0 = v0 - mu, d1 = v1 - mu;
    float var = block_sum256(d0 * d0 + d1 * d1, sm) * (1.f / 512.f);
    float rs = rsqrtf(var + 1e-5f);
    float o0 = d0 * rs * g[tid] + bta[tid];
    float o1 = d1 * rs * g[tid + 256] + bta[tid + 256];
    outf[(size_t)row * 512 + tid]       = o0;
    outf[(size_t)row * 512 + tid + 256] = o1;
    if (outb) {
        outb[(size_t)row * 512 + tid]       = f2bf(o0);
        outb[(size_t)row * 512 + tid + 256] = f2bf(o1);
    }
}

// ---------------------------------------------------------------------------
extern "C" void kernel_launch(void* const* d_in, const int* in_sizes, int n_in,
                              void* d_out, int out_size, void* d_ws, size_t ws_size,
                              hipStream_t stream)
{
    const float* x    = (const float*)d_in[0];
    const float* Wq   = (const float*)d_in[1];
    const float* bq   = (const float*)d_in[2];
    const float* Wk   = (const float*)d_in[3];
    const float* bk   = (const float*)d_in[4];
    const float* Wv   = (const float*)d_in[5];
    const float* bv   = (const float*)d_in[6];
    const float* Wo   = (const float*)d_in[7];
    const float* bo   = (const float*)d_in[8];
    const float* W1   = (const float*)d_in[9];
    const float* b1   = (const float*)d_in[10];
    const float* W2   = (const float*)d_in[11];
    const float* b2   = (const float*)d_in[12];
    const float* ln1g = (const float*)d_in[13];
    const float* ln1b = (const float*)d_in[14];
    const float* ln2g = (const float*)d_in[15];
    const float* ln2b = (const float*)d_in[16];

    const int S = 2048, D = 512, T = 4096, HD = 2048;

    char* w = (char*)d_ws;
    short* xb     = (short*)(w);                     // 4096x512 bf16
    short* QKVb   = (short*)(w + 4194304);           // 4096x1536 bf16
    short* wvb    = (short*)(w + 16777216);          // 4096x512 bf16
    float* tmpf   = (float*)(w + 20971520);          // 4096x512 f32
    float* x1f    = (float*)(w + 29360128);          // 4096x512 f32
    short* x1b    = (short*)(w + 37748736);          // 4096x512 bf16
    short* Wqkv_t = (short*)(w + 41943040);          // 1536x512 bf16
    short* Wo_t   = (short*)(w + 43515904);          // 512x512 bf16
    short* W1_t   = (short*)(w + 44040192);          // 2048x512 bf16
    short* W2_t   = (short*)(w + 46137344);          // 512x2048 bf16
    float* qbias  = (float*)(w + 48234496);          // 1536 f32
    short* hidb   = (short*)(w);                     // 4096x2048 bf16 (aliases xb+QKVb)

    float* out_x2 = (float*)d_out;
    float* heat   = out_x2 + (size_t)T * D;

    prep_kernel<<<dim3(5126), 256, 0, stream>>>(
        x, xb, Wq, Wk, Wv, Wo, W1, W2,
        Wqkv_t, Wo_t, W1_t, W2_t, bq, bk, bv, qbias);

    gemm2<2, 4><<<dim3(64, 12), 256, 0, stream>>>(
        xb, 512, Wqkv_t, 512, qbias, nullptr, nullptr, QKVb, 1536, 512, 0);

    attn_kernel<<<dim3(32, 16), 256, 0, stream>>>(QKVb, heat, wvb);

    gemm2<2, 2><<<dim3(64, 8), 256, 0, stream>>>(
        wvb, 512, Wo_t, 512, bo, x, tmpf, nullptr, 512, 512, 0);
    ln_kernel<<<dim3(T), 256, 0, stream>>>(tmpf, ln1g, ln1b, x1f, x1b);

    gemm2<2, 4><<<dim3(64, 16), 256, 0, stream>>>(
        x1b, 512, W1_t, 512, b1, nullptr, nullptr, hidb, HD, 512, 1);
    gemm2<2, 2><<<dim3(64, 8), 256, 0, stream>>>(
        hidb, 2048, W2_t, 2048, b2, x1f, tmpf, nullptr, 512, 2048, 0);
    ln_kernel<<<dim3(T), 256, 0, stream>>>(tmpf, ln2g, ln2b, out_x2, nullptr);
}